// Round 1
// baseline (354.985 us; speedup 1.0000x reference)
//
#include <hip/hip_runtime.h>

#define NB 16
#define DMODEL 4096
#define NH 32
#define NKV 8
#define HD 128
#define SEQ 4096
#define PASTN 4095
#define EQKV 6144           // 4096 q + 1024 k + 1024 v rows
#define NCHUNK 8
#define CHUNKS 512
#define STILE 32
#define SCALE 0.08838834764831845f  // 1/sqrt(128)

// ---------------- Kernel 1: fused QKV projection (M=16, N=6144, K=4096) ----
// 4 waves/block, each wave computes 4 output rows for all 16 batches.
__global__ __launch_bounds__(256) void qkv_proj(
    const float* __restrict__ hs, const float* __restrict__ Wq,
    const float* __restrict__ Wk, const float* __restrict__ Wv,
    float* __restrict__ raw /* [B][6144] */) {
  __shared__ float red[4][32][65];
  const int wid = threadIdx.x >> 6, lane = threadIdx.x & 63;
  const int e0 = (blockIdx.x * 4 + wid) * 4;

  const float* wrow[4];
#pragma unroll
  for (int r = 0; r < 4; ++r) {
    int e = e0 + r;
    wrow[r] = (e < 4096) ? (Wq + (size_t)e * DMODEL)
            : (e < 5120) ? (Wk + (size_t)(e - 4096) * DMODEL)
                         : (Wv + (size_t)(e - 5120) * DMODEL);
  }

  float acc[4][16];
#pragma unroll
  for (int r = 0; r < 4; ++r)
#pragma unroll
    for (int b = 0; b < 16; ++b) acc[r][b] = 0.f;

  for (int k0 = 0; k0 < DMODEL; k0 += 256) {
    const int k = k0 + lane * 4;
    float4 w4[4];
#pragma unroll
    for (int r = 0; r < 4; ++r) w4[r] = *(const float4*)(wrow[r] + k);
#pragma unroll
    for (int b = 0; b < 16; ++b) {
      float4 h4 = *(const float4*)(hs + (size_t)b * DMODEL + k);
#pragma unroll
      for (int r = 0; r < 4; ++r)
        acc[r][b] += w4[r].x * h4.x + w4[r].y * h4.y + w4[r].z * h4.z + w4[r].w * h4.w;
    }
  }

  // fold lane and lane+32 together, then LDS transpose-reduce
#pragma unroll
  for (int r = 0; r < 4; ++r)
#pragma unroll
    for (int b = 0; b < 16; ++b) acc[r][b] += __shfl_xor(acc[r][b], 32);

  if (lane < 32) {
#pragma unroll
    for (int r = 0; r < 4; ++r)
#pragma unroll
      for (int b = 0; b < 16; ++b) red[wid][lane][r * 16 + b] = acc[r][b];
  }
  __syncthreads();

  float sum = 0.f;
  for (int l = 0; l < 32; ++l) sum += red[wid][l][lane];
  const int r = lane >> 4, b = lane & 15;
  raw[(size_t)b * EQKV + e0 + r] = sum;
}

// ---------------- Kernel 2: RoPE + scatter new row into caches ------------
__device__ __forceinline__ float rope_val(const float* src, int d, float pos) {
  int i = d & 63;
  float inv_freq = powf(10000.f, -(float)(2 * i) * (1.f / 128.f));
  float ang = pos * inv_freq;
  float s, c;
  sincosf(ang, &s, &c);
  float x = src[d];
  float rot = (d < 64) ? -src[d + 64] : src[d - 64];
  return x * c + rot * s;
}

__global__ void rope_scatter(const float* __restrict__ raw,
                             const void* __restrict__ pos_ids,
                             float* __restrict__ qout,
                             float* __restrict__ kc, float* __restrict__ vc) {
  const int b = blockIdx.y, j = blockIdx.x, d = threadIdx.x;  // 128 threads
  const int* pi = (const int*)pos_ids;
  long long pos = (pi[1] == 0 && pi[0] != 0) ? ((const long long*)pos_ids)[b]
                                             : (long long)pi[b];
  const float fpos = (float)pos;
  if (j < 32) {
    const float* src = raw + (size_t)b * EQKV + j * HD;
    qout[(size_t)b * (NH * HD) + j * HD + d] = rope_val(src, d, fpos);
  } else if (j < 40) {
    int kvh = j - 32;
    const float* src = raw + (size_t)b * EQKV + 4096 + kvh * HD;
    kc[(((size_t)b * NKV + kvh) * SEQ + PASTN) * HD + d] = rope_val(src, d, fpos);
  } else {
    int kvh = j - 40;
    vc[(((size_t)b * NKV + kvh) * SEQ + PASTN) * HD + d] =
        raw[(size_t)b * EQKV + 5120 + kvh * HD + d];
  }
}

// ---------------- Kernel 3: fused cache-copy + flash-decode attention -----
// grid (chunk=8, kv=8, b=16); 256 threads = 4 waves = 4 heads per kv group.
__global__ __launch_bounds__(256) void attn_decode(
    const float* __restrict__ pastK, const float* __restrict__ pastV,
    const float* __restrict__ qv, const float* __restrict__ mask,
    float* __restrict__ kc, float* __restrict__ vc,
    float* __restrict__ part /* [B][32][8][130] */) {
  __shared__ float kt[STILE][129];
  __shared__ float vt[STILE][129];
  __shared__ float qs[4][HD];
  __shared__ float ps[4][STILE];

  const int chunk = blockIdx.x, kv = blockIdx.y, b = blockIdx.z;
  const int tid = threadIdx.x, wid = tid >> 6, lane = tid & 63;
  const int half = lane >> 5, sl = lane & 31;

  for (int i = tid; i < 4 * HD; i += 256)
    qs[i >> 7][i & 127] = qv[(size_t)b * (NH * HD) + (kv * 4 + (i >> 7)) * HD + (i & 127)];

  float m = -1e30f, l = 0.f, c0 = 0.f, c1 = 0.f;
  __syncthreads();

  for (int t = 0; t < CHUNKS / STILE; ++t) {
    const int s0 = chunk * CHUNKS + t * STILE;
    // stage K,V tile: global -> (cache write-through) -> LDS
#pragma unroll
    for (int i = 0; i < 4; ++i) {
      int g = i * 256 + tid;            // 0..1023
      int row = g >> 5, c4 = g & 31;    // 32 rows x 32 float4
      int s = s0 + row;
      size_t coff = (((size_t)b * NKV + kv) * SEQ + s) * HD + c4 * 4;
      float4 kvl, vvl;
      if (s < PASTN) {
        size_t poff = (((size_t)b * NKV + kv) * PASTN + s) * HD + c4 * 4;
        kvl = *(const float4*)(pastK + poff);
        vvl = *(const float4*)(pastV + poff);
        *(float4*)(kc + coff) = kvl;
        *(float4*)(vc + coff) = vvl;
      } else {  // s == 4095: new row already written by rope_scatter
        kvl = *(const float4*)(kc + coff);
        vvl = *(const float4*)(vc + coff);
      }
      *(float4*)(&kt[row][c4 * 4]) = kvl;
      *(float4*)(&vt[row][c4 * 4]) = vvl;
    }
    __syncthreads();

    // scores: lane half computes 64 dims, fold via shfl_xor(32)
    float dot = 0.f;
    const float* qrow = &qs[wid][half * 64];
    const float* krow = &kt[sl][half * 64];
#pragma unroll 16
    for (int d = 0; d < 64; ++d) dot += qrow[d] * krow[d];
    dot += __shfl_xor(dot, 32);

    const int s = s0 + sl;
    float sc = dot * SCALE + mask[(size_t)b * SEQ + s];

    float tm = sc;
#pragma unroll
    for (int o = 16; o >= 1; o >>= 1) tm = fmaxf(tm, __shfl_xor(tm, o));
    float mn = fmaxf(m, tm);
    float p = __expf(sc - mn);
    float alpha = __expf(m - mn);
    float psum = p;
#pragma unroll
    for (int o = 16; o >= 1; o >>= 1) psum += __shfl_xor(psum, o);
    l = l * alpha + psum;
    c0 *= alpha;
    c1 *= alpha;
    m = mn;

    if (half == 0) ps[wid][sl] = p;
    // wave-local LDS RAW; compiler inserts lgkmcnt
    for (int sp = 0; sp < STILE; ++sp) {
      float pv = ps[wid][sp];
      c0 += pv * vt[sp][lane];
      c1 += pv * vt[sp][64 + lane];
    }
    __syncthreads();
  }

  const int h = kv * 4 + wid;
  float* pp = part + (((size_t)b * NH + h) * NCHUNK + chunk) * 130;
  if (lane == 0) { pp[0] = m; pp[1] = l; }
  pp[2 + lane] = c0;
  pp[2 + 64 + lane] = c1;
}

// ---------------- Kernel 4: combine chunk partials ------------------------
__global__ void combine(const float* __restrict__ part, float* __restrict__ ctx) {
  const int bh = blockIdx.x;        // 0..511
  const int lane = threadIdx.x;     // 64
  const float* pp = part + (size_t)bh * NCHUNK * 130;
  float mstar = -1e30f;
#pragma unroll
  for (int c = 0; c < NCHUNK; ++c) mstar = fmaxf(mstar, pp[c * 130]);
  float den = 0.f, n0 = 0.f, n1 = 0.f;
#pragma unroll
  for (int c = 0; c < NCHUNK; ++c) {
    float w = __expf(pp[c * 130] - mstar);
    den += w * pp[c * 130 + 1];
    n0 += w * pp[c * 130 + 2 + lane];
    n1 += w * pp[c * 130 + 2 + 64 + lane];
  }
  float inv = 1.0f / den;
  ctx[(size_t)bh * HD + lane] = n0 * inv;
  ctx[(size_t)bh * HD + 64 + lane] = n1 * inv;
}

// ---------------- Kernel 5: output projection (M=16, N=4096, K=4096) ------
__global__ __launch_bounds__(256) void out_proj(
    const float* __restrict__ ctx, const float* __restrict__ Wo,
    float* __restrict__ out) {
  __shared__ float red[4][32][65];
  const int wid = threadIdx.x >> 6, lane = threadIdx.x & 63;
  const int r0 = (blockIdx.x * 4 + wid) * 4;

  float acc[4][16];
#pragma unroll
  for (int r = 0; r < 4; ++r)
#pragma unroll
    for (int b = 0; b < 16; ++b) acc[r][b] = 0.f;

  for (int k0 = 0; k0 < DMODEL; k0 += 256) {
    const int k = k0 + lane * 4;
    float4 w4[4];
#pragma unroll
    for (int r = 0; r < 4; ++r)
      w4[r] = *(const float4*)(Wo + (size_t)(r0 + r) * DMODEL + k);
#pragma unroll
    for (int b = 0; b < 16; ++b) {
      float4 h4 = *(const float4*)(ctx + (size_t)b * DMODEL + k);
#pragma unroll
      for (int r = 0; r < 4; ++r)
        acc[r][b] += w4[r].x * h4.x + w4[r].y * h4.y + w4[r].z * h4.z + w4[r].w * h4.w;
    }
  }

#pragma unroll
  for (int r = 0; r < 4; ++r)
#pragma unroll
    for (int b = 0; b < 16; ++b) acc[r][b] += __shfl_xor(acc[r][b], 32);

  if (lane < 32) {
#pragma unroll
    for (int r = 0; r < 4; ++r)
#pragma unroll
      for (int b = 0; b < 16; ++b) red[wid][lane][r * 16 + b] = acc[r][b];
  }
  __syncthreads();

  float sum = 0.f;
  for (int l = 0; l < 32; ++l) sum += red[wid][l][lane];
  const int r = lane >> 4, b = lane & 15;
  out[(size_t)b * DMODEL + r0 + r] = sum;
}

// ---------------------------------------------------------------------------
extern "C" void kernel_launch(void* const* d_in, const int* in_sizes, int n_in,
                              void* d_out, int out_size, void* d_ws, size_t ws_size,
                              hipStream_t stream) {
  const float* hs    = (const float*)d_in[0];
  const float* mask  = (const float*)d_in[1];
  const void*  pos   = d_in[2];
  const float* pastK = (const float*)d_in[3];
  const float* pastV = (const float*)d_in[4];
  const float* Wq    = (const float*)d_in[5];
  const float* Wk    = (const float*)d_in[6];
  const float* Wv    = (const float*)d_in[7];
  const float* Wo    = (const float*)d_in[8];

  float* out  = (float*)d_out;
  float* attn = out;                                        // 16*4096
  float* kc   = out + (size_t)NB * DMODEL;                  // 16*8*4096*128
  float* vc   = kc + (size_t)NB * NKV * SEQ * HD;

  float* ws      = (float*)d_ws;
  float* ws_q    = ws;                                      // 65536
  float* ws_raw  = ws_q + (size_t)NB * NH * HD;             // 98304
  float* ws_part = ws_raw + (size_t)NB * EQKV;              // 16*32*8*130
  float* ws_ctx  = ws_part + (size_t)NB * NH * NCHUNK * 130;// 65536

  qkv_proj<<<EQKV / 16, 256, 0, stream>>>(hs, Wq, Wk, Wv, ws_raw);
  rope_scatter<<<dim3(48, NB), 128, 0, stream>>>(ws_raw, pos, ws_q, kc, vc);
  attn_decode<<<dim3(NCHUNK, NKV, NB), 256, 0, stream>>>(pastK, pastV, ws_q, mask,
                                                         kc, vc, ws_part);
  combine<<<NB * NH, 64, 0, stream>>>(ws_part, ws_ctx);
  out_proj<<<DMODEL / 16, 256, 0, stream>>>(ws_ctx, Wo, attn);
}